// Round 3
// baseline (1813.894 us; speedup 1.0000x reference)
//
#include <hip/hip_runtime.h>
#include <math.h>

#define LLEN 8192
#define DDIM 1024
#define NB   2
#define NMODE 512
#define MFFT 8192
#define KF_STRIDE 8208   // float2 per Kf row (8193 used)

// ---------------- workspace layout (bytes), total ~172.4 MB ----------------
#define OFF_UT   ((size_t)0)            // u_T [B,D,L] f32 (y+res in place)  67,108,864
#define OFF_KF   ((size_t)67108864)     // Kf [D,KF_STRIDE] float2           67,239,936
#define OFF_KT   ((size_t)134348800)    // K_T [D,L] f32                     33,554,432
#define OFF_CPR  ((size_t)167903232)    // C'r [D,N] f32                      2,097,152
#define OFF_CPI  ((size_t)170000384)    // C'i [D,N] f32                      2,097,152
#define OFF_MEAN ((size_t)172097536)    // mean [B,L] f32                        65,536
#define OFF_RSTD ((size_t)172163072)    // rstd [B,L] f32                        65,536
#define OFF_LAMR ((size_t)172228608)    // f32[512]
#define OFF_LAMID ((size_t)172230656)   // f64[512] (4096 B)
#define OFF_WR   ((size_t)172234752)    // f32[512]
#define OFF_WI   ((size_t)172236800)    // f32[512]
#define OFF_CUT  ((size_t)172238848)    // int[512]
#define OFF_TW   ((size_t)172240896)    // twH: 8192 float2 (hierarchical)      65,536
#define OFF_TWR  ((size_t)172306432)    // 8193 float2 (2pi k/16384)            65,544
#define WS_NEED  ((size_t)172371976)

// ---------------- LayerNorm stats: mean/rstd per (b,l) row ----------------
__global__ __launch_bounds__(256) void ln_stats_kernel(const float* __restrict__ x,
                                                       float* __restrict__ mean,
                                                       float* __restrict__ rstd) {
  __shared__ float red[16];
  int row = blockIdx.x;            // b*L + l
  int tid = threadIdx.x;
  const float4* xr = (const float4*)(x + (size_t)row * DDIM);
  float4 v = xr[tid];
  float s = v.x + v.y + v.z + v.w;
  float q = v.x*v.x + v.y*v.y + v.z*v.z + v.w*v.w;
  #pragma unroll
  for (int off = 32; off; off >>= 1) { s += __shfl_down(s, off); q += __shfl_down(q, off); }
  int wid = tid >> 6;
  if ((tid & 63) == 0) { red[wid] = s; red[8 + wid] = q; }
  __syncthreads();
  if (tid == 0) {
    float ts = red[0] + red[1] + red[2] + red[3];
    float tq = red[8] + red[9] + red[10] + red[11];
    float m = ts * (1.0f / DDIM);
    float var = tq * (1.0f / DDIM) - m * m;
    mean[row] = m;
    rstd[row] = rsqrtf(var + 1e-5f);
  }
}

// ---------------- fused LN + transpose: x[B,L,D] -> uT[B,D,L] ----------------
__global__ __launch_bounds__(256) void transpose_ln_kernel(const float* __restrict__ x,
                                                           const float* __restrict__ mean,
                                                           const float* __restrict__ rstd,
                                                           const float* __restrict__ gamma,
                                                           const float* __restrict__ beta,
                                                           float* __restrict__ uT) {
  __shared__ float tile[32][33];
  int lt = blockIdx.x * 32, dt = blockIdx.y * 32, b = blockIdx.z;
  int c = threadIdx.x & 31, r0 = threadIdx.x >> 5;
  float gv = gamma[dt + c], bv = beta[dt + c];
  #pragma unroll
  for (int i = 0; i < 4; i++) {
    int r = r0 + i * 8;   // l within tile
    float m = mean[(size_t)b * LLEN + lt + r];
    float rs = rstd[(size_t)b * LLEN + lt + r];
    float xv = x[((size_t)b * LLEN + lt + r) * DDIM + dt + c];
    tile[r][c] = (xv - m) * rs * gv + bv;
  }
  __syncthreads();
  #pragma unroll
  for (int i = 0; i < 4; i++) {
    int r = r0 + i * 8;   // d within tile
    uT[((size_t)b * DDIM + dt + r) * LLEN + lt + c] = tile[c][r];
  }
}

// ---------------- params + twiddle tables (all one-time, double precision) ----------------
__global__ void build_tables_kernel(const float* __restrict__ Lr, const float* __restrict__ Li,
                                    float* lamr, double* lamid, float* wre, float* wim, int* cut,
                                    float2* twH, float2* twR) {
  int gid = blockIdx.x * 256 + threadIdx.x;
  if (gid < NMODE) {
    double lr = (double)Lr[gid], li = (double)Li[gid];
    double ar = -exp(lr);      // Re(Lam)  (negative)
    double ai = exp(li);       // Im(Lam)
    lamr[gid] = (float)ar;
    lamid[gid] = ai;
    double em = exp(ar);
    double cs = cos(ai), sn = sin(ai);
    double er = em * cs - 1.0;     // exp(Lam) - 1
    double ei = em * sn;
    double den = ar * ar + ai * ai;
    wre[gid] = (float)((er * ar + ei * ai) / den);   // (exp(Lam)-1)/Lam
    wim[gid] = (float)((ei * ar - er * ai) / den);
    int co = (int)(40.0 / (-ar)) + 1;                // exp(ar*l) < e^-40 beyond
    cut[gid] = co > LLEN ? LLEN : co;
  }
  int j = gid - NMODE;
  if (j >= 0 && j < 8192) {
    // hierarchical twiddle: twH[Ls + p] = (cos(pi*p/Ls), +sin(pi*p/Ls)).
    // Core applies wi = sign*w.y: sign=-1 (fwd) -> e^{-i a}, sign=+1 (inv) -> e^{+i a}.
    if (j == 0) {
      twH[0] = make_float2(1.f, 0.f);
    } else {
      int lev = 31 - __clz(j);
      int Ls = 1 << lev;
      int p = j - Ls;
      double a = 3.14159265358979323846264338 * (double)p / (double)Ls;
      twH[j] = make_float2((float)cos(a), (float)sin(a));   // POSITIVE sin (bug fix)
    }
  }
  int k = gid - (NMODE + 8192);
  if (k >= 0 && k <= 8192) {
    double a = 6.283185307179586476925287 * (double)k / 16384.0;
    twR[k] = make_float2((float)cos(a), (float)sin(a));
  }
}

// ---------------- C' = (Cr + iCi) * W ----------------
__global__ __launch_bounds__(256) void cprime_kernel(const float* __restrict__ Cr,
                                                     const float* __restrict__ Ci,
                                                     const float* __restrict__ wre,
                                                     const float* __restrict__ wim,
                                                     float* __restrict__ Cpr,
                                                     float* __restrict__ Cpi) {
  int idx = blockIdx.x * 256 + threadIdx.x;   // d*N + n
  int n = idx & (NMODE - 1);
  float cr = Cr[idx], ci = Ci[idx];
  float wr = wre[n], wi = wim[n];
  Cpr[idx] = cr * wr - ci * wi;
  Cpi[idx] = cr * wi + ci * wr;
}

// ---------------- K_T[d,l] = Re(sum_n C'[d,n] exp(Lam_n l)), S computed on the fly ----------------
#define KB_NC 8
__global__ __launch_bounds__(256) void kbuild_kernel(const float* __restrict__ lamr,
                                                     const double* __restrict__ lamid,
                                                     const int* __restrict__ cut,
                                                     const float* __restrict__ Cpr,
                                                     const float* __restrict__ Cpi,
                                                     float* __restrict__ KT) {
  __shared__ float sCr[32][KB_NC], sCi[32][KB_NC];
  __shared__ float slamr[NMODE];
  __shared__ double slami[NMODE];
  __shared__ int scut[NMODE];
  int tid = threadIdx.x;
  int l0 = blockIdx.x * 256;
  int d0 = blockIdx.y * 32;
  int l = l0 + tid;
  for (int i = tid; i < NMODE; i += 256) {
    scut[i] = cut[i]; slamr[i] = lamr[i]; slami[i] = lamid[i];
  }
  float acc[32];
  #pragma unroll
  for (int i = 0; i < 32; i++) acc[i] = 0.f;
  __syncthreads();
  const double tp = 6.283185307179586476925287;
  const double itp = 1.0 / 6.283185307179586476925287;
  for (int n0 = 0; n0 < NMODE; n0 += KB_NC) {
    bool active = false;   // block-uniform
    #pragma unroll
    for (int j = 0; j < KB_NC; j++) active |= (scut[n0 + j] > l0);
    if (!active) continue;
    __syncthreads();
    {
      int dd = tid >> 3, j = tid & 7;
      sCr[dd][j] = Cpr[(size_t)(d0 + dd) * NMODE + n0 + j];
      sCi[dd][j] = Cpi[(size_t)(d0 + dd) * NMODE + n0 + j];
    }
    __syncthreads();
    #pragma unroll
    for (int j = 0; j < KB_NC; j++) {
      int n = n0 + j;
      if (scut[n] <= l0) continue;   // block-uniform
      float sr = 0.f, si = 0.f;
      if (l < scut[n]) {
        float mag = expf(slamr[n] * (float)l);
        double ph = slami[n] * (double)l;
        ph -= floor(ph * itp) * tp;
        float cs, sn; sincosf((float)ph, &sn, &cs);
        sr = mag * cs; si = mag * sn;
      }
      #pragma unroll
      for (int dd = 0; dd < 32; dd++)
        acc[dd] += sr * sCr[dd][j] - si * sCi[dd][j];
    }
  }
  #pragma unroll
  for (int dd = 0; dd < 32; dd++)
    KT[(size_t)(d0 + dd) * LLEN + l] = acc[dd];
}

// ---------------- 8192-pt complex Stockham FFT in LDS ----------------
// natural order in/out; result ends in bufB. sign=-1 fwd, +1 inv (unnormalized).
// twH[Ls+p] = (cos(pi p/Ls), +sin(pi p/Ls)); effective twiddle = (w.x, sign*w.y).
__device__ __forceinline__ void fft8192_core(float2* bufA, float2* bufB,
                                             const float2* __restrict__ twH,
                                             int tid, float sign) {
  float2* src = bufA;
  float2* dst = bufB;
  #pragma unroll 1
  for (int s = 0; s < 13; ++s) {
    int Ls = 1 << s;
    __syncthreads();
    #pragma unroll
    for (int it = 0; it < 4; ++it) {
      int j = tid + it * 1024;            // butterfly id < 4096
      int p = j & (Ls - 1);
      int q = j >> s;
      float2 w = twH[Ls + p];
      float wr = w.x, wi = sign * w.y;    // fwd: e^{-ia}, inv: e^{+ia}
      float2 a = src[j];
      float2 b = src[j + 4096];
      float br = wr * b.x - wi * b.y;
      float bi = wr * b.y + wi * b.x;
      int o = (q << (s + 1)) + p;
      dst[o]      = make_float2(a.x + br, a.y + bi);
      dst[o + Ls] = make_float2(a.x - br, a.y - bi);
    }
    float2* tsw = src; src = dst; dst = tsw;
  }
  __syncthreads();
}

// ---------------- Kf[d,k] = rfft16384(K_T[d]) / 8192, k=0..8192 ----------------
__global__ __launch_bounds__(1024) void kf_fft_kernel(const float* __restrict__ KT,
                                                      const float2* __restrict__ twH,
                                                      const float2* __restrict__ twR,
                                                      float2* __restrict__ Kf) {
  __shared__ float2 bufA[MFFT];
  __shared__ float2 bufB[MFFT];
  int d = blockIdx.x;
  int tid = threadIdx.x;
  const float2* row = (const float2*)(KT + (size_t)d * LLEN);
  for (int j = tid; j < MFFT; j += 1024)
    bufA[j] = (j < 4096) ? row[j] : make_float2(0.f, 0.f);
  fft8192_core(bufA, bufB, twH, tid, -1.f);   // Z in bufB
  const float scale = 1.0f / 8192.0f;         // fold inverse-FFT 1/8192 here
  float2* out = Kf + (size_t)d * KF_STRIDE;
  for (int k = tid; k <= 4096; k += 1024) {
    if (k == 0) {
      float2 z0 = bufB[0];
      out[0]    = make_float2((z0.x + z0.y) * scale, 0.f);
      out[8192] = make_float2((z0.x - z0.y) * scale, 0.f);
    } else {
      float2 zk = bufB[k];
      float2 zm = bufB[MFFT - k];
      float Ar = 0.5f * (zk.x + zm.x), Ai = 0.5f * (zk.y - zm.y);
      float Br = 0.5f * (zk.x - zm.x), Bi = 0.5f * (zk.y + zm.y);
      float2 t = twR[k];
      float c = t.x, sn = t.y;
      float e1r = sn * Br - c * Bi;
      float e1i = sn * Bi + c * Br;
      out[k]        = make_float2((Ar - e1r) * scale, (Ai - e1i) * scale);
      out[MFFT - k] = make_float2((Ar + e1r) * scale, (-Ai - e1i) * scale);
    }
  }
}

// ---------------- conv: y = irfft(rfft(u) * Kf) + u*pD, in-place over uT row ----------------
__global__ __launch_bounds__(1024) void conv_fft_kernel(float* __restrict__ uT,
                                                        const float2* __restrict__ twH,
                                                        const float2* __restrict__ twR,
                                                        const float2* __restrict__ Kf,
                                                        const float* __restrict__ pD) {
  __shared__ float2 bufA[MFFT];
  __shared__ float2 bufB[MFFT];
  int wg = blockIdx.x;
  int b = wg >> 10, d = wg & (DDIM - 1);
  int tid = threadIdx.x;
  float2* row = (float2*)(uT + ((size_t)b * DDIM + d) * LLEN);
  for (int j = tid; j < MFFT; j += 1024)
    bufA[j] = (j < 4096) ? row[j] : make_float2(0.f, 0.f);
  fft8192_core(bufA, bufB, twH, tid, -1.f);   // Z in bufB
  const float2* kf = Kf + (size_t)d * KF_STRIDE;
  for (int k = tid; k <= 4096; k += 1024) {
    if (k == 0) {
      float2 z0 = bufB[0];
      float U0 = z0.x + z0.y;
      float UM = z0.x - z0.y;
      float Y0 = U0 * kf[0].x;
      float YM = UM * kf[8192].x;
      bufA[0] = make_float2(0.5f * (Y0 + YM), 0.5f * (Y0 - YM));
    } else {
      float2 zk = bufB[k];
      float2 zm = bufB[MFFT - k];
      float Ar = 0.5f * (zk.x + zm.x), Ai = 0.5f * (zk.y - zm.y);
      float Br = 0.5f * (zk.x - zm.x), Bi = 0.5f * (zk.y + zm.y);
      float2 t = twR[k];
      float c = t.x, sn = t.y;
      float e1r = sn * Br - c * Bi;
      float e1i = sn * Bi + c * Br;
      float Ukr = Ar - e1r, Uki = Ai - e1i;      // U[k]
      float Umr = Ar + e1r, Umi = -Ai - e1i;     // U[8192-k]
      float2 kk = kf[k], km = kf[MFFT - k];
      float Ykr = Ukr * kk.x - Uki * kk.y, Yki = Ukr * kk.y + Uki * kk.x;
      float Ymr = Umr * km.x - Umi * km.y, Ymi = Umr * km.y + Umi * km.x;
      float Eyr = 0.5f * (Ykr + Ymr), Eyi = 0.5f * (Yki - Ymi);
      float Byr = 0.5f * (Ykr - Ymr), Byi = 0.5f * (Yki + Ymi);
      bufA[k]        = make_float2(Eyr - sn * Byr - c * Byi, Eyi + c * Byr - sn * Byi);
      bufA[MFFT - k] = make_float2(Eyr + sn * Byr + c * Byi, -Eyi + c * Byr - sn * Byi);
    }
  }
  __syncthreads();
  fft8192_core(bufA, bufB, twH, tid, +1.f);   // z_y in bufB (1/8192 folded into Kf)
  float pdv = pD[d];
  for (int j = tid; j < 4096; j += 1024) {
    float2 uv = row[j];                        // original u (untouched so far)
    float2 yv = bufB[j];
    row[j] = make_float2(yv.x + uv.x * pdv, yv.y + uv.y * pdv);
  }
}

// ---------------- out[b,l,d] = yT[b,d,l] (transpose back) ----------------
__global__ __launch_bounds__(256) void final_kernel(const float* __restrict__ yT,
                                                    float* __restrict__ out) {
  __shared__ float tile[32][33];
  int lt = blockIdx.x * 32, dt = blockIdx.y * 32, b = blockIdx.z;
  int c = threadIdx.x & 31, r0 = threadIdx.x >> 5;
  #pragma unroll
  for (int i = 0; i < 4; i++) {
    int r = r0 + i * 8;   // d within tile
    tile[r][c] = yT[((size_t)b * DDIM + dt + r) * LLEN + lt + c];
  }
  __syncthreads();
  #pragma unroll
  for (int i = 0; i < 4; i++) {
    int r = r0 + i * 8;   // l within tile
    out[((size_t)b * LLEN + lt + r) * DDIM + dt + c] = tile[c][r];
  }
}

extern "C" void kernel_launch(void* const* d_in, const int* in_sizes, int n_in,
                              void* d_out, int out_size, void* d_ws, size_t ws_size,
                              hipStream_t stream) {
  (void)in_sizes; (void)n_in; (void)out_size;
  if (ws_size < WS_NEED) return;   // safety: fail cleanly (wrong output) instead of faulting
  const float* x     = (const float*)d_in[0];
  const float* Lr    = (const float*)d_in[1];
  const float* Li    = (const float*)d_in[2];
  const float* Cr    = (const float*)d_in[3];
  const float* Ci    = (const float*)d_in[4];
  const float* pD    = (const float*)d_in[5];
  const float* gamma = (const float*)d_in[6];
  const float* beta  = (const float*)d_in[7];
  float* out = (float*)d_out;
  char* ws = (char*)d_ws;

  float*  UT    = (float*)(ws + OFF_UT);
  float2* KF    = (float2*)(ws + OFF_KF);
  float*  KT    = (float*)(ws + OFF_KT);
  float*  CPR   = (float*)(ws + OFF_CPR);
  float*  CPI   = (float*)(ws + OFF_CPI);
  float*  MEAN  = (float*)(ws + OFF_MEAN);
  float*  RSTD  = (float*)(ws + OFF_RSTD);
  float*  LAMR  = (float*)(ws + OFF_LAMR);
  double* LAMID = (double*)(ws + OFF_LAMID);
  float*  WRe   = (float*)(ws + OFF_WR);
  float*  WIm   = (float*)(ws + OFF_WI);
  int*    CUT   = (int*)(ws + OFF_CUT);
  float2* TWH   = (float2*)(ws + OFF_TW);
  float2* TWR   = (float2*)(ws + OFF_TWR);

  ln_stats_kernel<<<NB * LLEN, 256, 0, stream>>>(x, MEAN, RSTD);
  transpose_ln_kernel<<<dim3(LLEN / 32, DDIM / 32, NB), 256, 0, stream>>>(x, MEAN, RSTD, gamma, beta, UT);
  build_tables_kernel<<<67, 256, 0, stream>>>(Lr, Li, LAMR, LAMID, WRe, WIm, CUT, TWH, TWR);
  cprime_kernel<<<(DDIM * NMODE) / 256, 256, 0, stream>>>(Cr, Ci, WRe, WIm, CPR, CPI);
  kbuild_kernel<<<dim3(LLEN / 256, DDIM / 32), 256, 0, stream>>>(LAMR, LAMID, CUT, CPR, CPI, KT);
  kf_fft_kernel<<<DDIM, 1024, 0, stream>>>(KT, TWH, TWR, KF);
  conv_fft_kernel<<<NB * DDIM, 1024, 0, stream>>>(UT, TWH, TWR, KF, pD);
  final_kernel<<<dim3(LLEN / 32, DDIM / 32, NB), 256, 0, stream>>>(UT, out);
}

// Round 4
// 673.494 us; speedup vs baseline: 2.6933x; 2.6933x over previous
//
#include <hip/hip_runtime.h>
#include <math.h>

#define LLEN 8192
#define DDIM 1024
#define NB   2
#define NMODE 512
#define MFFT 8192
#define KF_STRIDE 8208   // float2 per Kf row (8193 used)

// ---------------- workspace layout (bytes), total ~172.4 MB ----------------
#define OFF_UT   ((size_t)0)            // u_T [B,D,L] f32 (y+res in place)  67,108,864
#define OFF_KF   ((size_t)67108864)     // Kf [D,KF_STRIDE] float2           67,239,936
                                        //   (Sr/Si [512][8192] f32 overlaid here
                                        //    before kf_fft runs: 33,554,432 x2)
#define OFF_KT   ((size_t)134348800)    // K_T [D,L] f32                     33,554,432
#define OFF_CPR  ((size_t)167903232)    // C'r [D,N] f32                      2,097,152
#define OFF_CPI  ((size_t)170000384)    // C'i [D,N] f32                      2,097,152
#define OFF_MEAN ((size_t)172097536)    // mean [B,L] f32                        65,536
#define OFF_RSTD ((size_t)172163072)    // rstd [B,L] f32                        65,536
#define OFF_LAMR ((size_t)172228608)    // f32[512]
#define OFF_LAMID ((size_t)172230656)   // f64[512] (4096 B)
#define OFF_WR   ((size_t)172234752)    // f32[512]
#define OFF_WI   ((size_t)172236800)    // f32[512]
#define OFF_CUT  ((size_t)172238848)    // int[512]
#define OFF_TW   ((size_t)172240896)    // twH: 8192 float2 (hierarchical)      65,536
#define OFF_TWR  ((size_t)172306432)    // 8193 float2 (2pi k/16384)            65,544
#define WS_NEED  ((size_t)172371976)

// Sr/Si overlay inside the KF region (dead until kf_fft writes KF)
#define OFF_SR   OFF_KF
#define OFF_SI   (OFF_KF + (size_t)33554432)

// ---------------- LayerNorm stats: mean/rstd per (b,l) row ----------------
__global__ __launch_bounds__(256) void ln_stats_kernel(const float* __restrict__ x,
                                                       float* __restrict__ mean,
                                                       float* __restrict__ rstd) {
  __shared__ float red[16];
  int row = blockIdx.x;            // b*L + l
  int tid = threadIdx.x;
  const float4* xr = (const float4*)(x + (size_t)row * DDIM);
  float4 v = xr[tid];
  float s = v.x + v.y + v.z + v.w;
  float q = v.x*v.x + v.y*v.y + v.z*v.z + v.w*v.w;
  #pragma unroll
  for (int off = 32; off; off >>= 1) { s += __shfl_down(s, off); q += __shfl_down(q, off); }
  int wid = tid >> 6;
  if ((tid & 63) == 0) { red[wid] = s; red[8 + wid] = q; }
  __syncthreads();
  if (tid == 0) {
    float ts = red[0] + red[1] + red[2] + red[3];
    float tq = red[8] + red[9] + red[10] + red[11];
    float m = ts * (1.0f / DDIM);
    float var = tq * (1.0f / DDIM) - m * m;
    mean[row] = m;
    rstd[row] = rsqrtf(var + 1e-5f);
  }
}

// ---------------- fused LN + transpose: x[B,L,D] -> uT[B,D,L] ----------------
__global__ __launch_bounds__(256) void transpose_ln_kernel(const float* __restrict__ x,
                                                           const float* __restrict__ mean,
                                                           const float* __restrict__ rstd,
                                                           const float* __restrict__ gamma,
                                                           const float* __restrict__ beta,
                                                           float* __restrict__ uT) {
  __shared__ float tile[32][33];
  int lt = blockIdx.x * 32, dt = blockIdx.y * 32, b = blockIdx.z;
  int c = threadIdx.x & 31, r0 = threadIdx.x >> 5;
  float gv = gamma[dt + c], bv = beta[dt + c];
  #pragma unroll
  for (int i = 0; i < 4; i++) {
    int r = r0 + i * 8;   // l within tile
    float m = mean[(size_t)b * LLEN + lt + r];
    float rs = rstd[(size_t)b * LLEN + lt + r];
    float xv = x[((size_t)b * LLEN + lt + r) * DDIM + dt + c];
    tile[r][c] = (xv - m) * rs * gv + bv;
  }
  __syncthreads();
  #pragma unroll
  for (int i = 0; i < 4; i++) {
    int r = r0 + i * 8;   // d within tile
    uT[((size_t)b * DDIM + dt + r) * LLEN + lt + c] = tile[c][r];
  }
}

// ---------------- params + twiddle tables (all one-time, double precision) ----------------
__global__ void build_tables_kernel(const float* __restrict__ Lr, const float* __restrict__ Li,
                                    float* lamr, double* lamid, float* wre, float* wim, int* cut,
                                    float2* twH, float2* twR) {
  int gid = blockIdx.x * 256 + threadIdx.x;
  if (gid < NMODE) {
    double lr = (double)Lr[gid], li = (double)Li[gid];
    double ar = -exp(lr);      // Re(Lam)  (negative)
    double ai = exp(li);       // Im(Lam)
    lamr[gid] = (float)ar;
    lamid[gid] = ai;
    double em = exp(ar);
    double cs = cos(ai), sn = sin(ai);
    double er = em * cs - 1.0;     // exp(Lam) - 1
    double ei = em * sn;
    double den = ar * ar + ai * ai;
    wre[gid] = (float)((er * ar + ei * ai) / den);   // (exp(Lam)-1)/Lam
    wim[gid] = (float)((ei * ar - er * ai) / den);
    int co = (int)(40.0 / (-ar)) + 1;                // exp(ar*l) < e^-40 beyond
    cut[gid] = co > LLEN ? LLEN : co;
  }
  int j = gid - NMODE;
  if (j >= 0 && j < 8192) {
    // hierarchical twiddle: twH[Ls + p] = (cos(pi*p/Ls), +sin(pi*p/Ls)).
    // Core applies wi = sign*w.y: sign=-1 (fwd) -> e^{-i a}, sign=+1 (inv) -> e^{+i a}.
    if (j == 0) {
      twH[0] = make_float2(1.f, 0.f);
    } else {
      int lev = 31 - __clz(j);
      int Ls = 1 << lev;
      int p = j - Ls;
      double a = 3.14159265358979323846264338 * (double)p / (double)Ls;
      twH[j] = make_float2((float)cos(a), (float)sin(a));
    }
  }
  int k = gid - (NMODE + 8192);
  if (k >= 0 && k <= 8192) {
    double a = 6.283185307179586476925287 * (double)k / 16384.0;
    twR[k] = make_float2((float)cos(a), (float)sin(a));
  }
}

// ---------------- C' = (Cr + iCi) * W ----------------
__global__ __launch_bounds__(256) void cprime_kernel(const float* __restrict__ Cr,
                                                     const float* __restrict__ Ci,
                                                     const float* __restrict__ wre,
                                                     const float* __restrict__ wim,
                                                     float* __restrict__ Cpr,
                                                     float* __restrict__ Cpi) {
  int idx = blockIdx.x * 256 + threadIdx.x;   // d*N + n
  int n = idx & (NMODE - 1);
  float cr = Cr[idx], ci = Ci[idx];
  float wr = wre[n], wi = wim[n];
  Cpr[idx] = cr * wr - ci * wi;
  Cpi[idx] = cr * wi + ci * wr;
}

// ---------------- S[n,l] = exp(Lam_n l), zero-padded beyond cut ----------------
__global__ __launch_bounds__(256) void sbuild_kernel(const float* __restrict__ lamr,
                                                     const double* __restrict__ lamid,
                                                     const int* __restrict__ cut,
                                                     float* __restrict__ Sr,
                                                     float* __restrict__ Si) {
  int n = blockIdx.y;
  int l = blockIdx.x * 256 + threadIdx.x;
  float sr = 0.f, si = 0.f;
  if (l < cut[n]) {
    float mag = expf(lamr[n] * (float)l);
    double ph = lamid[n] * (double)l;
    const double tp = 6.283185307179586476925287;
    const double itp = 1.0 / 6.283185307179586476925287;
    ph -= floor(ph * itp) * tp;
    float cs, sn; sincosf((float)ph, &sn, &cs);
    sr = mag * cs; si = mag * sn;
  }
  Sr[(size_t)n * LLEN + l] = sr;
  Si[(size_t)n * LLEN + l] = si;
}

// ---------------- KT[d,l] = sum_n Cpr[d,n]*Sr[n,l] - Cpi[d,n]*Si[n,l] ----------------
// Register-tiled: d-tile 16, l-tile 1024 (4 l per thread), 128-mode LDS-staged chunks.
#define KB2_DT 16
#define KB2_LT 1024
#define KB2_NCH 128
__global__ __launch_bounds__(256) void kbuild2_kernel(const float* __restrict__ Sr,
                                                      const float* __restrict__ Si,
                                                      const float* __restrict__ Cpr,
                                                      const float* __restrict__ Cpi,
                                                      const int* __restrict__ cut,
                                                      float* __restrict__ KT) {
  __shared__ float sCr[KB2_NCH][KB2_DT + 1], sCi[KB2_NCH][KB2_DT + 1];
  __shared__ int scut[NMODE];
  int tid = threadIdx.x;
  int l0 = blockIdx.x * KB2_LT;
  int d0 = blockIdx.y * KB2_DT;
  for (int i = tid; i < NMODE; i += 256) scut[i] = cut[i];
  float acc[KB2_DT][4];
  #pragma unroll
  for (int dd = 0; dd < KB2_DT; ++dd) {
    #pragma unroll
    for (int k = 0; k < 4; ++k) acc[dd][k] = 0.f;
  }
  __syncthreads();
  for (int ch = 0; ch < NMODE / KB2_NCH; ++ch) {
    bool chact = false;                       // block-uniform
    for (int j = 0; j < KB2_NCH; ++j) chact |= (scut[ch * KB2_NCH + j] > l0);
    if (!chact) continue;
    __syncthreads();
    for (int i = tid; i < KB2_NCH * KB2_DT; i += 256) {
      int n = i & (KB2_NCH - 1);
      int dd = i >> 7;
      sCr[n][dd] = Cpr[(size_t)(d0 + dd) * NMODE + ch * KB2_NCH + n];
      sCi[n][dd] = Cpi[(size_t)(d0 + dd) * NMODE + ch * KB2_NCH + n];
    }
    __syncthreads();
    for (int j = 0; j < KB2_NCH; ++j) {
      int n = ch * KB2_NCH + j;
      if (scut[n] <= l0) continue;            // block-uniform; S is zero-padded so exact
      const float* srp = Sr + (size_t)n * LLEN + l0 + tid;
      const float* sip = Si + (size_t)n * LLEN + l0 + tid;
      float sr0 = srp[0],   si0 = sip[0];
      float sr1 = srp[256], si1 = sip[256];
      float sr2 = srp[512], si2 = sip[512];
      float sr3 = srp[768], si3 = sip[768];
      #pragma unroll
      for (int dd = 0; dd < KB2_DT; ++dd) {
        float cr = sCr[j][dd], ci = sCi[j][dd];
        acc[dd][0] += sr0 * cr - si0 * ci;
        acc[dd][1] += sr1 * cr - si1 * ci;
        acc[dd][2] += sr2 * cr - si2 * ci;
        acc[dd][3] += sr3 * cr - si3 * ci;
      }
    }
  }
  #pragma unroll
  for (int dd = 0; dd < KB2_DT; ++dd) {
    size_t base = (size_t)(d0 + dd) * LLEN + l0 + tid;
    KT[base]       = acc[dd][0];
    KT[base + 256] = acc[dd][1];
    KT[base + 512] = acc[dd][2];
    KT[base + 768] = acc[dd][3];
  }
}

// ---------------- 8192-pt complex Stockham FFT in LDS ----------------
// natural order in/out; result ends in bufB. sign=-1 fwd, +1 inv (unnormalized).
// twH[Ls+p] = (cos(pi p/Ls), +sin(pi p/Ls)); effective twiddle = (w.x, sign*w.y).
__device__ __forceinline__ void fft8192_core(float2* bufA, float2* bufB,
                                             const float2* __restrict__ twH,
                                             int tid, float sign) {
  float2* src = bufA;
  float2* dst = bufB;
  #pragma unroll 1
  for (int s = 0; s < 13; ++s) {
    int Ls = 1 << s;
    __syncthreads();
    #pragma unroll
    for (int it = 0; it < 4; ++it) {
      int j = tid + it * 1024;            // butterfly id < 4096
      int p = j & (Ls - 1);
      int q = j >> s;
      float2 w = twH[Ls + p];
      float wr = w.x, wi = sign * w.y;    // fwd: e^{-ia}, inv: e^{+ia}
      float2 a = src[j];
      float2 b = src[j + 4096];
      float br = wr * b.x - wi * b.y;
      float bi = wr * b.y + wi * b.x;
      int o = (q << (s + 1)) + p;
      dst[o]      = make_float2(a.x + br, a.y + bi);
      dst[o + Ls] = make_float2(a.x - br, a.y - bi);
    }
    float2* tsw = src; src = dst; dst = tsw;
  }
  __syncthreads();
}

// ---------------- Kf[d,k] = rfft16384(K_T[d]) / 8192, k=0..8192 ----------------
__global__ __launch_bounds__(1024) void kf_fft_kernel(const float* __restrict__ KT,
                                                      const float2* __restrict__ twH,
                                                      const float2* __restrict__ twR,
                                                      float2* __restrict__ Kf) {
  __shared__ float2 bufA[MFFT];
  __shared__ float2 bufB[MFFT];
  int d = blockIdx.x;
  int tid = threadIdx.x;
  const float2* row = (const float2*)(KT + (size_t)d * LLEN);
  for (int j = tid; j < MFFT; j += 1024)
    bufA[j] = (j < 4096) ? row[j] : make_float2(0.f, 0.f);
  fft8192_core(bufA, bufB, twH, tid, -1.f);   // Z in bufB
  const float scale = 1.0f / 8192.0f;         // fold inverse-FFT 1/8192 here
  float2* out = Kf + (size_t)d * KF_STRIDE;
  for (int k = tid; k <= 4096; k += 1024) {
    if (k == 0) {
      float2 z0 = bufB[0];
      out[0]    = make_float2((z0.x + z0.y) * scale, 0.f);
      out[8192] = make_float2((z0.x - z0.y) * scale, 0.f);
    } else {
      float2 zk = bufB[k];
      float2 zm = bufB[MFFT - k];
      float Ar = 0.5f * (zk.x + zm.x), Ai = 0.5f * (zk.y - zm.y);
      float Br = 0.5f * (zk.x - zm.x), Bi = 0.5f * (zk.y + zm.y);
      float2 t = twR[k];
      float c = t.x, sn = t.y;
      float e1r = sn * Br - c * Bi;
      float e1i = sn * Bi + c * Br;
      out[k]        = make_float2((Ar - e1r) * scale, (Ai - e1i) * scale);
      out[MFFT - k] = make_float2((Ar + e1r) * scale, (-Ai - e1i) * scale);
    }
  }
}

// ---------------- conv: y = irfft(rfft(u) * Kf) + u*pD, in-place over uT row ----------------
__global__ __launch_bounds__(1024) void conv_fft_kernel(float* __restrict__ uT,
                                                        const float2* __restrict__ twH,
                                                        const float2* __restrict__ twR,
                                                        const float2* __restrict__ Kf,
                                                        const float* __restrict__ pD) {
  __shared__ float2 bufA[MFFT];
  __shared__ float2 bufB[MFFT];
  int wg = blockIdx.x;
  int b = wg >> 10, d = wg & (DDIM - 1);
  int tid = threadIdx.x;
  float2* row = (float2*)(uT + ((size_t)b * DDIM + d) * LLEN);
  for (int j = tid; j < MFFT; j += 1024)
    bufA[j] = (j < 4096) ? row[j] : make_float2(0.f, 0.f);
  fft8192_core(bufA, bufB, twH, tid, -1.f);   // Z in bufB
  const float2* kf = Kf + (size_t)d * KF_STRIDE;
  for (int k = tid; k <= 4096; k += 1024) {
    if (k == 0) {
      float2 z0 = bufB[0];
      float U0 = z0.x + z0.y;
      float UM = z0.x - z0.y;
      float Y0 = U0 * kf[0].x;
      float YM = UM * kf[8192].x;
      bufA[0] = make_float2(0.5f * (Y0 + YM), 0.5f * (Y0 - YM));
    } else {
      float2 zk = bufB[k];
      float2 zm = bufB[MFFT - k];
      float Ar = 0.5f * (zk.x + zm.x), Ai = 0.5f * (zk.y - zm.y);
      float Br = 0.5f * (zk.x - zm.x), Bi = 0.5f * (zk.y + zm.y);
      float2 t = twR[k];
      float c = t.x, sn = t.y;
      float e1r = sn * Br - c * Bi;
      float e1i = sn * Bi + c * Br;
      float Ukr = Ar - e1r, Uki = Ai - e1i;      // U[k]
      float Umr = Ar + e1r, Umi = -Ai - e1i;     // U[8192-k]
      float2 kk = kf[k], km = kf[MFFT - k];
      float Ykr = Ukr * kk.x - Uki * kk.y, Yki = Ukr * kk.y + Uki * kk.x;
      float Ymr = Umr * km.x - Umi * km.y, Ymi = Umr * km.y + Umi * km.x;
      float Eyr = 0.5f * (Ykr + Ymr), Eyi = 0.5f * (Yki - Ymi);
      float Byr = 0.5f * (Ykr - Ymr), Byi = 0.5f * (Yki + Ymi);
      bufA[k]        = make_float2(Eyr - sn * Byr - c * Byi, Eyi + c * Byr - sn * Byi);
      bufA[MFFT - k] = make_float2(Eyr + sn * Byr + c * Byi, -Eyi + c * Byr - sn * Byi);
    }
  }
  __syncthreads();
  fft8192_core(bufA, bufB, twH, tid, +1.f);   // z_y in bufB (1/8192 folded into Kf)
  float pdv = pD[d];
  for (int j = tid; j < 4096; j += 1024) {
    float2 uv = row[j];                        // original u (untouched so far)
    float2 yv = bufB[j];
    row[j] = make_float2(yv.x + uv.x * pdv, yv.y + uv.y * pdv);
  }
}

// ---------------- out[b,l,d] = yT[b,d,l] (transpose back) ----------------
__global__ __launch_bounds__(256) void final_kernel(const float* __restrict__ yT,
                                                    float* __restrict__ out) {
  __shared__ float tile[32][33];
  int lt = blockIdx.x * 32, dt = blockIdx.y * 32, b = blockIdx.z;
  int c = threadIdx.x & 31, r0 = threadIdx.x >> 5;
  #pragma unroll
  for (int i = 0; i < 4; i++) {
    int r = r0 + i * 8;   // d within tile
    tile[r][c] = yT[((size_t)b * DDIM + dt + r) * LLEN + lt + c];
  }
  __syncthreads();
  #pragma unroll
  for (int i = 0; i < 4; i++) {
    int r = r0 + i * 8;   // l within tile
    out[((size_t)b * LLEN + lt + r) * DDIM + dt + c] = tile[c][r];
  }
}

extern "C" void kernel_launch(void* const* d_in, const int* in_sizes, int n_in,
                              void* d_out, int out_size, void* d_ws, size_t ws_size,
                              hipStream_t stream) {
  (void)in_sizes; (void)n_in; (void)out_size;
  if (ws_size < WS_NEED) return;   // safety: fail cleanly (wrong output) instead of faulting
  const float* x     = (const float*)d_in[0];
  const float* Lr    = (const float*)d_in[1];
  const float* Li    = (const float*)d_in[2];
  const float* Cr    = (const float*)d_in[3];
  const float* Ci    = (const float*)d_in[4];
  const float* pD    = (const float*)d_in[5];
  const float* gamma = (const float*)d_in[6];
  const float* beta  = (const float*)d_in[7];
  float* out = (float*)d_out;
  char* ws = (char*)d_ws;

  float*  UT    = (float*)(ws + OFF_UT);
  float2* KF    = (float2*)(ws + OFF_KF);
  float*  SRb   = (float*)(ws + OFF_SR);    // overlaid on KF region
  float*  SIb   = (float*)(ws + OFF_SI);    // overlaid on KF region
  float*  KT    = (float*)(ws + OFF_KT);
  float*  CPR   = (float*)(ws + OFF_CPR);
  float*  CPI   = (float*)(ws + OFF_CPI);
  float*  MEAN  = (float*)(ws + OFF_MEAN);
  float*  RSTD  = (float*)(ws + OFF_RSTD);
  float*  LAMR  = (float*)(ws + OFF_LAMR);
  double* LAMID = (double*)(ws + OFF_LAMID);
  float*  WRe   = (float*)(ws + OFF_WR);
  float*  WIm   = (float*)(ws + OFF_WI);
  int*    CUT   = (int*)(ws + OFF_CUT);
  float2* TWH   = (float2*)(ws + OFF_TW);
  float2* TWR   = (float2*)(ws + OFF_TWR);

  ln_stats_kernel<<<NB * LLEN, 256, 0, stream>>>(x, MEAN, RSTD);
  transpose_ln_kernel<<<dim3(LLEN / 32, DDIM / 32, NB), 256, 0, stream>>>(x, MEAN, RSTD, gamma, beta, UT);
  build_tables_kernel<<<67, 256, 0, stream>>>(Lr, Li, LAMR, LAMID, WRe, WIm, CUT, TWH, TWR);
  cprime_kernel<<<(DDIM * NMODE) / 256, 256, 0, stream>>>(Cr, Ci, WRe, WIm, CPR, CPI);
  sbuild_kernel<<<dim3(LLEN / 256, NMODE), 256, 0, stream>>>(LAMR, LAMID, CUT, SRb, SIb);
  kbuild2_kernel<<<dim3(LLEN / KB2_LT, DDIM / KB2_DT), 256, 0, stream>>>(SRb, SIb, CPR, CPI, CUT, KT);
  kf_fft_kernel<<<DDIM, 1024, 0, stream>>>(KT, TWH, TWR, KF);   // KF overwrites S region (S dead now)
  conv_fft_kernel<<<NB * DDIM, 1024, 0, stream>>>(UT, TWH, TWR, KF, pD);
  final_kernel<<<dim3(LLEN / 32, DDIM / 32, NB), 256, 0, stream>>>(UT, out);
}